// Round 1
// baseline (1436.808 us; speedup 1.0000x reference)
//
#include <hip/hip_runtime.h>
#include <hip/hip_bf16.h>

#define B_ 4
#define S_ 2048
#define D_ 1024
#define E_ 8
#define V_ 32000
#define H_ 4096
#define M_ (B_ * S_)   // 8192 tokens
#define EPS_ 1e-5f

typedef float floatx4 __attribute__((ext_vector_type(4)));
typedef __bf16 bf16x8 __attribute__((ext_vector_type(8)));

// ---------------- async global->LDS (width 16) ----------------
__device__ __forceinline__ void async_copy16(void* lds, const void* g) {
    __builtin_amdgcn_global_load_lds(
        (const __attribute__((address_space(1))) void*)g,
        (__attribute__((address_space(3))) void*)lds,
        16, 0, 0);
}

// ---------------- helpers ----------------
__device__ __forceinline__ float gelu_tanh(float v) {
    float u = 0.7978845608028654f * (v + 0.044715f * v * v * v);
    // tanh(u) = 1 - 2/(exp(2u)+1); saturates correctly at +-inf
    float t = 1.0f - 2.0f / (__expf(2.0f * u) + 1.0f);
    return 0.5f * v * (1.0f + t);
}

__device__ __forceinline__ float block_sum256(float v, float* sm4) {
#pragma unroll
    for (int o = 32; o > 0; o >>= 1) v += __shfl_down(v, o, 64);
    int wave = threadIdx.x >> 6;
    __syncthreads();                       // protect sm4 reuse across calls
    if ((threadIdx.x & 63) == 0) sm4[wave] = v;
    __syncthreads();
    return sm4[0] + sm4[1] + sm4[2] + sm4[3];
}

// ---------------- transpose + f32->bf16 convert ----------------
// in: R x C (f32, row-major) -> out: C x R (bf16, row-major)
__global__ __launch_bounds__(256) void transpose_cvt_kernel(
    const float* __restrict__ in, __hip_bfloat16* __restrict__ out, int R, int C) {
    __shared__ float tile[32][33];
    int bx = blockIdx.x * 32, by = blockIdx.y * 32;
    int tx = threadIdx.x, ty = threadIdx.y;   // (32, 8)
#pragma unroll
    for (int j = 0; j < 32; j += 8)
        tile[ty + j][tx] = in[(long)(by + ty + j) * C + bx + tx];
    __syncthreads();
#pragma unroll
    for (int j = 0; j < 32; j += 8)
        out[(long)(bx + ty + j) * R + by + tx] = __float2bfloat16(tile[tx][ty + j]);
}

// ---------------- LN1 + router softmax + LN2 ----------------
// one block (256 threads) per token; each thread owns 4 elements (stride 256)
__global__ __launch_bounds__(256) void ln_router_kernel(
    const float* __restrict__ x,            // (M, D)
    const float* __restrict__ g1, const float* __restrict__ b1,
    const float* __restrict__ g2, const float* __restrict__ b2,
    const float* __restrict__ rw,           // (D, E)
    const float* __restrict__ rb,           // (E)
    float* __restrict__ rv,                 // (M, E) out
    __hip_bfloat16* __restrict__ h2) {      // (M, D) out bf16
    __shared__ float sm4[4];
    __shared__ float pws[4][E_];
    const int t = blockIdx.x;
    const int tid = threadIdx.x;
    const float* xr = x + (long)t * D_;

    float v[4];
    float s = 0.f;
#pragma unroll
    for (int i = 0; i < 4; ++i) { v[i] = xr[tid + 256 * i]; s += v[i]; }
    s = block_sum256(s, sm4);
    float mu = s * (1.0f / D_);
    float ss = 0.f;
#pragma unroll
    for (int i = 0; i < 4; ++i) { float d = v[i] - mu; ss += d * d; }
    ss = block_sum256(ss, sm4);
    float rs = rsqrtf(ss * (1.0f / D_) + EPS_);

    float h[4];
#pragma unroll
    for (int i = 0; i < 4; ++i) {
        int d = tid + 256 * i;
        h[i] = (v[i] - mu) * rs * g1[d] + b1[d];
    }

    // router logits: p[e] = sum_d h[d] * rw[d][e]
    float p[E_];
#pragma unroll
    for (int e = 0; e < E_; ++e) p[e] = 0.f;
#pragma unroll
    for (int i = 0; i < 4; ++i) {
        int d = tid + 256 * i;
#pragma unroll
        for (int e = 0; e < E_; ++e) p[e] += h[i] * rw[d * E_ + e];
    }
#pragma unroll
    for (int e = 0; e < E_; ++e) {
        float pe = p[e];
#pragma unroll
        for (int o = 32; o > 0; o >>= 1) pe += __shfl_down(pe, o, 64);
        p[e] = pe;
    }
    __syncthreads();
    if ((tid & 63) == 0) {
#pragma unroll
        for (int e = 0; e < E_; ++e) pws[tid >> 6][e] = p[e];
    }
    __syncthreads();
    float logit[E_];
#pragma unroll
    for (int e = 0; e < E_; ++e)
        logit[e] = pws[0][e] + pws[1][e] + pws[2][e] + pws[3][e] + rb[e];
    float mx = logit[0];
#pragma unroll
    for (int e = 1; e < E_; ++e) mx = fmaxf(mx, logit[e]);
    float ex[E_], se = 0.f;
#pragma unroll
    for (int e = 0; e < E_; ++e) { ex[e] = __expf(logit[e] - mx); se += ex[e]; }
    float inv = 1.0f / se;
    if (tid < E_) rv[(long)t * E_ + tid] = ex[tid] * inv;

    // LN2 over h
    float s2 = 0.f;
#pragma unroll
    for (int i = 0; i < 4; ++i) s2 += h[i];
    s2 = block_sum256(s2, sm4);
    float mu2 = s2 * (1.0f / D_);
    float ss2 = 0.f;
#pragma unroll
    for (int i = 0; i < 4; ++i) { float d = h[i] - mu2; ss2 += d * d; }
    ss2 = block_sum256(ss2, sm4);
    float rs2 = rsqrtf(ss2 * (1.0f / D_) + EPS_);
#pragma unroll
    for (int i = 0; i < 4; ++i) {
        int d = tid + 256 * i;
        h2[(long)t * D_ + d] = __float2bfloat16((h[i] - mu2) * rs2 * g2[d] + b2[d]);
    }
}

// ---------------- GEMM1: C = A(M,K) @ Bt(N,K)^T, bias + gelu -> bf16 ----------------
// 128x128 tile, K-tile 32, 4 waves (2x2), each wave 64x64 via 4x4 mfma 16x16x32
__global__ __launch_bounds__(256) void gemm1_kernel(
    const __hip_bfloat16* __restrict__ A,   // (M, K)  h2
    const __hip_bfloat16* __restrict__ Bt,  // (N, K)  w1^T
    const float* __restrict__ bias,         // (N)
    __hip_bfloat16* __restrict__ out,       // (M, N)  act
    int M, int N, int K) {
    __shared__ __align__(16) __hip_bfloat16 As[128 * 32];
    __shared__ __align__(16) __hip_bfloat16 Bs[128 * 32];
    const int tid = threadIdx.x;
    const int lane = tid & 63;
    const int wave = tid >> 6;
    const int wm = wave >> 1, wn = wave & 1;
    const int q = lane >> 4, l15 = lane & 15;
    const int m0 = blockIdx.x * 128, n0 = blockIdx.y * 128;

    const int c0 = tid, c1 = 256 + tid;
    const __hip_bfloat16* ga0 = A + (long)(m0 + (c0 >> 2)) * K + (c0 & 3) * 8;
    const __hip_bfloat16* ga1 = A + (long)(m0 + (c1 >> 2)) * K + (c1 & 3) * 8;
    const __hip_bfloat16* gb0 = Bt + (long)(n0 + (c0 >> 2)) * K + (c0 & 3) * 8;
    const __hip_bfloat16* gb1 = Bt + (long)(n0 + (c1 >> 2)) * K + (c1 & 3) * 8;
    __hip_bfloat16* la0 = As + c0 * 8;
    __hip_bfloat16* la1 = As + c1 * 8;
    __hip_bfloat16* lb0 = Bs + c0 * 8;
    __hip_bfloat16* lb1 = Bs + c1 * 8;

    const __hip_bfloat16* pa = As + (wm * 64 + l15) * 32 + q * 8;
    const __hip_bfloat16* pb = Bs + (wn * 64 + l15) * 32 + q * 8;

    floatx4 acc[4][4] = {};

    for (int k0 = 0; k0 < K; k0 += 32) {
        async_copy16(la0, ga0 + k0);
        async_copy16(la1, ga1 + k0);
        async_copy16(lb0, gb0 + k0);
        async_copy16(lb1, gb1 + k0);
        __syncthreads();
        bf16x8 af[4], bf[4];
#pragma unroll
        for (int i = 0; i < 4; ++i) af[i] = *(const bf16x8*)(pa + i * 16 * 32);
#pragma unroll
        for (int j = 0; j < 4; ++j) bf[j] = *(const bf16x8*)(pb + j * 16 * 32);
#pragma unroll
        for (int i = 0; i < 4; ++i)
#pragma unroll
            for (int j = 0; j < 4; ++j)
                acc[i][j] = __builtin_amdgcn_mfma_f32_16x16x32_bf16(af[i], bf[j], acc[i][j], 0, 0, 0);
        __syncthreads();
    }

#pragma unroll
    for (int i = 0; i < 4; ++i) {
#pragma unroll
        for (int j = 0; j < 4; ++j) {
            int n = n0 + wn * 64 + j * 16 + l15;
            float bn = bias[n];
#pragma unroll
            for (int r = 0; r < 4; ++r) {
                int m = m0 + wm * 64 + i * 16 + q * 4 + r;
                float v = acc[i][j][r] + bn;
                out[(long)m * N + n] = __float2bfloat16(gelu_tanh(v));
            }
        }
    }
}

// ---------------- GEMM2 + fused epilogue (bias + residual + routed) ----------------
__global__ __launch_bounds__(256) void gemm2_kernel(
    const __hip_bfloat16* __restrict__ A,    // act (M, K)
    const __hip_bfloat16* __restrict__ Bt,   // w2^T (N, K)
    const float* __restrict__ bias,          // b2 (N)
    const float* __restrict__ residual,      // (M, D)
    const float* __restrict__ lut,           // (V, E*D)
    const int* __restrict__ ids,             // (M)
    const float* __restrict__ rv,            // (M, E)
    float* __restrict__ out,                 // (M, D)
    int M, int N, int K) {
    __shared__ __align__(16) __hip_bfloat16 As[128 * 32];
    __shared__ __align__(16) __hip_bfloat16 Bs[128 * 32];
    __shared__ float rvs[128][E_];
    __shared__ long rowbase[128];
    const int tid = threadIdx.x;
    const int lane = tid & 63;
    const int wave = tid >> 6;
    const int wm = wave >> 1, wn = wave & 1;
    const int q = lane >> 4, l15 = lane & 15;
    const int m0 = blockIdx.x * 128, n0 = blockIdx.y * 128;

    const int c0 = tid, c1 = 256 + tid;
    const __hip_bfloat16* ga0 = A + (long)(m0 + (c0 >> 2)) * K + (c0 & 3) * 8;
    const __hip_bfloat16* ga1 = A + (long)(m0 + (c1 >> 2)) * K + (c1 & 3) * 8;
    const __hip_bfloat16* gb0 = Bt + (long)(n0 + (c0 >> 2)) * K + (c0 & 3) * 8;
    const __hip_bfloat16* gb1 = Bt + (long)(n0 + (c1 >> 2)) * K + (c1 & 3) * 8;
    __hip_bfloat16* la0 = As + c0 * 8;
    __hip_bfloat16* la1 = As + c1 * 8;
    __hip_bfloat16* lb0 = Bs + c0 * 8;
    __hip_bfloat16* lb1 = Bs + c1 * 8;

    const __hip_bfloat16* pa = As + (wm * 64 + l15) * 32 + q * 8;
    const __hip_bfloat16* pb = Bs + (wn * 64 + l15) * 32 + q * 8;

    floatx4 acc[4][4] = {};

    for (int k0 = 0; k0 < K; k0 += 32) {
        async_copy16(la0, ga0 + k0);
        async_copy16(la1, ga1 + k0);
        async_copy16(lb0, gb0 + k0);
        async_copy16(lb1, gb1 + k0);
        __syncthreads();
        bf16x8 af[4], bf[4];
#pragma unroll
        for (int i = 0; i < 4; ++i) af[i] = *(const bf16x8*)(pa + i * 16 * 32);
#pragma unroll
        for (int j = 0; j < 4; ++j) bf[j] = *(const bf16x8*)(pb + j * 16 * 32);
#pragma unroll
        for (int i = 0; i < 4; ++i)
#pragma unroll
            for (int j = 0; j < 4; ++j)
                acc[i][j] = __builtin_amdgcn_mfma_f32_16x16x32_bf16(af[i], bf[j], acc[i][j], 0, 0, 0);
        __syncthreads();
    }

    // stage this tile's token metadata (128 tokens) into LDS
    if (tid < 128) {
        int m = m0 + tid;
        rowbase[tid] = (long)ids[m] * (E_ * D_);
#pragma unroll
        for (int e = 0; e < E_; ++e) rvs[tid][e] = rv[(long)m * E_ + e];
    }
    __syncthreads();

#pragma unroll
    for (int i = 0; i < 4; ++i) {
#pragma unroll
        for (int r = 0; r < 4; ++r) {
            int ml = wm * 64 + i * 16 + q * 4 + r;   // local token index
            int m = m0 + ml;
            const float* lr = lut + rowbase[ml];
#pragma unroll
            for (int j = 0; j < 4; ++j) {
                int n = n0 + wn * 64 + j * 16 + l15;
                float routed = 0.f;
#pragma unroll
                for (int e = 0; e < E_; ++e)
                    routed += rvs[ml][e] * lr[e * D_ + n];
                float v = acc[i][j][r] + bias[n] + residual[(long)m * D_ + n] + routed;
                out[(long)m * D_ + n] = v;
            }
        }
    }
}

extern "C" void kernel_launch(void* const* d_in, const int* in_sizes, int n_in,
                              void* d_out, int out_size, void* d_ws, size_t ws_size,
                              hipStream_t stream) {
    const float* hs    = (const float*)d_in[0];
    const int*   ids   = (const int*)d_in[1];
    const float* lut   = (const float*)d_in[2];
    const float* ln1g  = (const float*)d_in[3];
    const float* ln1b  = (const float*)d_in[4];
    const float* ln2g  = (const float*)d_in[5];
    const float* ln2b  = (const float*)d_in[6];
    const float* rw    = (const float*)d_in[7];
    const float* rb    = (const float*)d_in[8];
    const float* w1    = (const float*)d_in[9];
    const float* b1    = (const float*)d_in[10];
    const float* w2    = (const float*)d_in[11];
    const float* b2    = (const float*)d_in[12];
    float* out = (float*)d_out;

    char* ws = (char*)d_ws;
    // ws layout (bytes), all 16B-aligned:
    __hip_bfloat16* h2  = (__hip_bfloat16*)(ws);                         // 16 MB  (M*D bf16)
    __hip_bfloat16* w1t = (__hip_bfloat16*)(ws + 16777216);              // 8 MB   (H*D bf16)
    __hip_bfloat16* w2t = (__hip_bfloat16*)(ws + 25165824);              // 8 MB   (D*H bf16)
    __hip_bfloat16* act = (__hip_bfloat16*)(ws + 33554432);              // 64 MB  (M*H bf16)
    float*          rv  = (float*)(ws + 100663296);                      // 256 KB (M*E f32)

    // w1 (D,H) -> w1t (H,D) bf16 ; w2 (H,D) -> w2t (D,H) bf16
    transpose_cvt_kernel<<<dim3(H_ / 32, D_ / 32), dim3(32, 8), 0, stream>>>(w1, w1t, D_, H_);
    transpose_cvt_kernel<<<dim3(D_ / 32, H_ / 32), dim3(32, 8), 0, stream>>>(w2, w2t, H_, D_);

    ln_router_kernel<<<M_, 256, 0, stream>>>(hs, ln1g, ln1b, ln2g, ln2b, rw, rb, rv, h2);

    gemm1_kernel<<<dim3(M_ / 128, H_ / 128), 256, 0, stream>>>(h2, w1t, b1, act, M_, H_, D_);

    gemm2_kernel<<<dim3(M_ / 128, D_ / 128), 256, 0, stream>>>(act, w2t, b2, hs, lut, ids, rv, out,
                                                               M_, D_, H_);
}